// Round 7
// baseline (224.472 us; speedup 1.0000x reference)
//
#include <hip/hip_runtime.h>
#include <math.h>

#define T_N     4096
#define B_N     64
#define C_N     64
#define NFILT   2
#define F_BINS  2049
#define NPAIRS  2016
#define NFEAT   4032
#define NOUT    4
#define TSG     8
#define NKS     16            // (4096/TSG)/32 K-steps per gram block

#define PI_F 3.14159265358979323846f
#define W4096 (2.0f * PI_F / 4096.0f)
#define W256  (2.0f * PI_F / 256.0f)

typedef _Float16 f16x8 __attribute__((ext_vector_type(8)));
typedef float    f32x4 __attribute__((ext_vector_type(4)));

// ---------------------------------------------------------------------------
// Spectrum layout of the 3-phase register FFT (N = 16*16*16):
//   thread t = k1*16 + j1, register q = j2  holds bin k = q*256 + j1*16 + k1.
// Filter table stored at p(k) = (k & 0xF00) + ((k & 15) << 4) + ((k >> 4) & 15).
// Twiddles computed inline with __sincosf (|theta| < 2pi; accuracy proven in
// rounds 1-3 of this pipeline) — independent per k for ILP; NO global-table
// loads inside barrier-fenced phases (barrier drains vmcnt, so table-load
// latency was unhideable — r6 post-mortem).
// ---------------------------------------------------------------------------

// ---- ws layout (bytes) ----
#define OFF_U     65536
#define G_BYTES   (128 * TSG * 12288 * 4)

// ---------------- filter construction (1 block) ----------------
__global__ __launch_bounds__(256) void filter_kernel(
    const float* __restrict__ fm_, const float* __restrict__ bw_,
    const float* __restrict__ sp_, const float* __restrict__ gd_,
    float* __restrict__ filt) {
  __shared__ float smag[F_BINS];
  __shared__ float sred[256];
  const int tid = threadIdx.x;
  for (int f = 0; f < NFILT; ++f) {
    float* Fre = filt + f * 8192;
    float* Fim = Fre + 4096;
    for (int p = tid; p < 4096; p += 256) { Fre[p] = 0.0f; Fim[p] = 0.0f; }
    const float fm = fminf(fmaxf(fm_[f], 1.0f / 128.0f), 45.0f / 128.0f);
    const float bw = fminf(fmaxf(bw_[f], 1.0f / 128.0f), 1.0f);
    const float pp = fminf(fmaxf(sp_[f], 2.0f), 3.0f) * 8.0f - 14.0f;
    const float gd = gd_[f];
    const float scale = bw / (2.0f * powf(0.69314718055994531f, 1.0f / pp));
    float lmax = 0.0f;
    for (int i = tid; i < F_BINS; i += 256) {
      const float n = (float)i / 2048.0f;
      const float m = expf(-powf((fabsf(n - fm) + 1e-8f) / scale, pp));
      smag[i] = m;
      lmax = fmaxf(lmax, m);
    }
    sred[tid] = lmax;
    __syncthreads();
    for (int s = 128; s > 0; s >>= 1) {
      if (tid < s) sred[tid] = fmaxf(sred[tid], sred[tid + s]);
      __syncthreads();
    }
    const float inv = 1.0f / sred[0];
    __syncthreads();
    for (int k = tid; k < F_BINS; k += 256) {
      const float m = smag[k] * inv;
      const float pha = -gd * ((float)k * 0.125f) * PI_F;
      float sn, cs;
      sincosf(pha, &sn, &cs);
      const float dcs = (k == 0) ? 1.0f : 2.0f;
      const float sT = dcs * (1.0f / (float)T_N);
      const int p = (k & 0xF00) + ((k & 15) << 4) + ((k >> 4) & 15);
      Fre[p] = m * cs * sT;
      Fim[p] = m * sn * sT;
    }
    __syncthreads();
  }
}

// ---------------- complex helpers (float2, packable to v_pk_*_f32) ----------
__device__ __forceinline__ float2 cmul(float2 a, float c, float s) {
  return make_float2(a.x * c - a.y * s, a.x * s + a.y * c);
}

// ---------------- 16-point DFT, natural order in/out, in registers ----------
template<int SGN>
__device__ __forceinline__ void dft16(float2* __restrict__ v) {
  const float sg = (float)SGN;
  const float C1 = 0.923879532511287f, S1 = 0.382683432365090f;
  const float Hh = 0.707106781186548f;
  float2 g[16];
#pragma unroll
  for (int n2 = 0; n2 < 4; ++n2) {
    const float2 a = v[n2], b = v[4 + n2], c = v[8 + n2], d = v[12 + n2];
    const float2 t0 = make_float2(a.x + c.x, a.y + c.y);
    const float2 t1 = make_float2(a.x - c.x, a.y - c.y);
    const float2 t2 = make_float2(b.x + d.x, b.y + d.y);
    const float2 t3 = make_float2(b.x - d.x, b.y - d.y);
    g[n2]      = make_float2(t0.x + t2.x, t0.y + t2.y);
    g[8 + n2]  = make_float2(t0.x - t2.x, t0.y - t2.y);
    g[4 + n2]  = make_float2(t1.x - sg * t3.y, t1.y + sg * t3.x);  // t1 + sg*i*t3
    g[12 + n2] = make_float2(t1.x + sg * t3.y, t1.y - sg * t3.x);  // t1 - sg*i*t3
  }
  g[5]  = cmul(g[5],  C1,  sg * S1);
  g[6]  = cmul(g[6],  Hh,  sg * Hh);
  g[7]  = cmul(g[7],  S1,  sg * C1);
  g[9]  = cmul(g[9],  Hh,  sg * Hh);
  g[10] = make_float2(-sg * g[10].y, sg * g[10].x);
  g[11] = cmul(g[11], -Hh, sg * Hh);
  g[13] = cmul(g[13], S1,  sg * C1);
  g[14] = cmul(g[14], -Hh, sg * Hh);
  g[15] = cmul(g[15], -C1, -sg * S1);
#pragma unroll
  for (int k1 = 0; k1 < 4; ++k1) {
    const float2 a = g[4 * k1], b = g[4 * k1 + 1];
    const float2 c = g[4 * k1 + 2], d = g[4 * k1 + 3];
    const float2 t0 = make_float2(a.x + c.x, a.y + c.y);
    const float2 t1 = make_float2(a.x - c.x, a.y - c.y);
    const float2 t2 = make_float2(b.x + d.x, b.y + d.y);
    const float2 t3 = make_float2(b.x - d.x, b.y - d.y);
    v[k1]      = make_float2(t0.x + t2.x, t0.y + t2.y);
    v[8 + k1]  = make_float2(t0.x - t2.x, t0.y - t2.y);
    v[4 + k1]  = make_float2(t1.x - sg * t3.y, t1.y + sg * t3.x);
    v[12 + k1] = make_float2(t1.x + sg * t3.y, t1.y - sg * t3.x);
  }
}

// transposes through padded float2 LDS (stride 264 -> ~2-way banks)
__device__ __forceinline__ void tr_cross_fwd(float2* __restrict__ v,
                                             float2* __restrict__ lds, int t) {
  __syncthreads();
#pragma unroll
  for (int k = 0; k < 16; ++k) lds[k * 264 + t] = v[k];
  __syncthreads();
  const int base = (t >> 4) * 264 + (t & 15);
#pragma unroll
  for (int m = 0; m < 16; ++m) v[m] = lds[base + m * 16];
}
__device__ __forceinline__ void tr_cross_inv(float2* __restrict__ v,
                                             float2* __restrict__ lds, int t) {
  __syncthreads();
  const int base = (t >> 4) * 264 + (t & 15);
#pragma unroll
  for (int m = 0; m < 16; ++m) lds[base + m * 16] = v[m];
  __syncthreads();
#pragma unroll
  for (int k = 0; k < 16; ++k) v[k] = lds[k * 264 + t];
}
__device__ __forceinline__ void tr_group(float2* __restrict__ v,
                                         float2* __restrict__ lds, int t) {
  __syncthreads();
  const int k1 = t >> 4, s = t & 15;
  const int rowb = k1 * 264;
#pragma unroll
  for (int r = 0; r < 16; ++r)
    lds[rowb + r * 16 + ((s + r) & 15)] = v[r];
  __syncthreads();
#pragma unroll
  for (int a = 0; a < 16; ++a)
    v[a] = lds[rowb + s * 16 + ((a + s) & 15)];
}

// ---------------- fwd FFT once + filter + 2x inverse FFT + normalize --------
__global__ __launch_bounds__(256) void fftfilt_kernel(
    const float* __restrict__ x, const float* __restrict__ filt,
    _Float16* __restrict__ Urg, _Float16* __restrict__ Uig, int chunkbase) {
  const int c  = blockIdx.x & 63;
  const int bb = blockIdx.x >> 6;
  const int b  = chunkbase + bb;
  const int t  = threadIdx.x;
  const int j1 = t & 15;
  __shared__ float2 lds[16 * 264];   // 33792 B

  float2 v[16];
  const float* xp = x + ((size_t)(b * C_N + c)) * T_N;
#pragma unroll
  for (int r = 0; r < 16; ++r) v[r] = make_float2(xp[r * 256 + t], 0.0f);

  // ---- forward ----
  dft16<-1>(v);
#pragma unroll
  for (int k = 1; k < 16; ++k) {               // chain A: e^{-2pi i t k/4096}
    float sn, cs;
    __sincosf(-W4096 * (float)(t * k), &sn, &cs);
    v[k] = cmul(v[k], cs, sn);
  }
  tr_cross_fwd(v, lds, t);
  dft16<-1>(v);
#pragma unroll
  for (int k = 1; k < 16; ++k) {               // chain B: e^{-2pi i j1 k/256}
    float sn, cs;
    __sincosf(-W256 * (float)(j1 * k), &sn, &cs);
    v[k] = cmul(v[k], cs, sn);
  }
  tr_group(v, lds, t);
  dft16<-1>(v);

  float2 X[16];
#pragma unroll
  for (int q = 0; q < 16; ++q) X[q] = v[q];

#pragma unroll 1
  for (int f = 0; f < NFILT; ++f) {
    const float* Fre = filt + f * 8192;
    const float* Fim = Fre + 4096;
#pragma unroll
    for (int q = 0; q < 16; ++q) {             // component-wise filter
      v[q] = make_float2(X[q].x * Fre[q * 256 + t], X[q].y * Fim[q * 256 + t]);
    }
    // ---- inverse (mirror dataflow, conj twiddles, unscaled) ----
    dft16<1>(v);
#pragma unroll
    for (int k = 1; k < 16; ++k) {             // chain B': e^{+2pi i j1 k/256}
      float sn, cs;
      __sincosf(W256 * (float)(j1 * k), &sn, &cs);
      v[k] = cmul(v[k], cs, sn);
    }
    tr_group(v, lds, t);
    dft16<1>(v);
    {
      const int k1 = t >> 4, m2 = t & 15;
#pragma unroll
      for (int m1 = 0; m1 < 16; ++m1) {        // chain C: e^{+2pi i k1(m2+16m1)/4096}
        float sn, cs;
        __sincosf(W4096 * (float)(k1 * (m2 + 16 * m1)), &sn, &cs);
        v[m1] = cmul(v[m1], cs, sn);
      }
    }
    tr_cross_inv(v, lds, t);
    dft16<1>(v);

    const int sl = bb * 2 + f;
    _Float16* upr = Urg + ((size_t)sl * C_N + c) * T_N;
    _Float16* upi = Uig + ((size_t)sl * C_N + c) * T_N;
#pragma unroll
    for (int n1 = 0; n1 < 16; ++n1) {
      const float ir = rsqrtf(v[n1].x * v[n1].x + v[n1].y * v[n1].y + 1e-6f);
      upr[n1 * 256 + t] = (_Float16)(v[n1].x * ir);
      upi[n1 * 256 + t] = (_Float16)(v[n1].y * ir);
    }
  }
}

// ---------------- gram via f16 MFMA -> per-tsplit partial planes ------------
__global__ __launch_bounds__(256) void gram_kernel(
    const _Float16* __restrict__ Urg, const _Float16* __restrict__ Uig,
    float* __restrict__ Gp, int slicebase) {
  const int sl = blockIdx.x / TSG;
  const int ts = blockIdx.x % TSG;
  const int tid = threadIdx.x;
  const int w = tid >> 6;
  const int lane = tid & 63;
  __shared__ _Float16 sUr[2][64 * 40], sUi[2][64 * 40];

  const int row = tid >> 2, quarter = tid & 3;
  const size_t goff = (size_t)sl * C_N * T_N + (size_t)row * T_N
                      + ts * (T_N / TSG) + quarter * 8;
  const int loff = row * 40 + quarter * 8;
  const int frow = (lane & 15) * 40 + (lane >> 4) * 8;
  const int aoff = w * 640 + frow;

  f32x4 accRr[4] = {}, accIi[4] = {}, accRi[4] = {};

  f16x8 rr = *(const f16x8*)&Urg[goff];
  f16x8 ri = *(const f16x8*)&Uig[goff];
  int cur = 0;
  for (int ks = 0; ks < NKS; ++ks) {
    *(f16x8*)&sUr[cur][loff] = rr;
    *(f16x8*)&sUi[cur][loff] = ri;
    if (ks + 1 < NKS) {
      rr = *(const f16x8*)&Urg[goff + (ks + 1) * 32];
      ri = *(const f16x8*)&Uig[goff + (ks + 1) * 32];
    }
    __syncthreads();
    const f16x8 ar = *(const f16x8*)&sUr[cur][aoff];
    const f16x8 ai = *(const f16x8*)&sUi[cur][aoff];
#pragma unroll
    for (int n = 0; n < 4; ++n) {
      const f16x8 br = *(const f16x8*)&sUr[cur][n * 640 + frow];
      const f16x8 bi = *(const f16x8*)&sUi[cur][n * 640 + frow];
      accRr[n] = __builtin_amdgcn_mfma_f32_16x16x32_f16(ar, br, accRr[n], 0, 0, 0);
      accIi[n] = __builtin_amdgcn_mfma_f32_16x16x32_f16(ai, bi, accIi[n], 0, 0, 0);
      accRi[n] = __builtin_amdgcn_mfma_f32_16x16x32_f16(ar, bi, accRi[n], 0, 0, 0);
    }
    cur ^= 1;
  }

  // plain stores into this block's own partial plane (no atomics)
  float* Gs = Gp + (size_t)((slicebase + sl) * TSG + ts) * 12288;
  const int r0 = w * 16 + (lane >> 4) * 4;
  const int c0 = lane & 15;
#pragma unroll
  for (int n = 0; n < 4; ++n) {
    const bool upper = (n >= w);   // strictly-below-diagonal Rr/Ii never read
#pragma unroll
    for (int e = 0; e < 4; ++e) {
      const int idx = (r0 + e) * 64 + n * 16 + c0;
      if (upper) {
        Gs[idx] = accRr[n][e];
        Gs[4096 + idx] = accIi[n][e];
      }
      Gs[8192 + idx] = accRi[n][e];
    }
  }
}

// ---------------- PLV (sums TSG partials) + scatter to feature layout -------
__global__ __launch_bounds__(256) void plv_kernel(
    const float* __restrict__ Gp, float* __restrict__ feats) {
  const int idx = blockIdx.x * 256 + threadIdx.x;
  if (idx >= B_N * NFILT * NPAIRS) return;
  const int slice = idx / NPAIRS;
  const int p = idx - slice * NPAIRS;
  const int b = slice >> 1, f = slice & 1;
  int c = 0, rem = p;
  while (rem >= 63 - c) { rem -= 63 - c; ++c; }
  const int d = c + 1 + rem;
  const float* Gs = Gp + (size_t)slice * TSG * 12288;
  float rr = 0, ii = 0, ri = 0, ir = 0;
#pragma unroll
  for (int ts = 0; ts < TSG; ++ts) {
    const float* P = Gs + ts * 12288;
    rr += P[c * 64 + d];
    ii += P[4096 + c * 64 + d];
    ri += P[8192 + c * 64 + d];
    ir += P[8192 + d * 64 + c];
  }
  const float cre = rr + ii;
  const float cim = ri - ir;
  const float plv = sqrtf(cre * cre + cim * cim + 1e-6f) * (1.0f / (float)T_N);
  feats[b * NFEAT + p * NFILT + f] = plv;
}

// ---------------- batch stats (training-mode BN, biased var) ----------------
__global__ __launch_bounds__(256) void stats_kernel(
    const float* __restrict__ feats, float* __restrict__ stats) {
  const int j = blockIdx.x * 256 + threadIdx.x;
  if (j >= NFEAT) return;
  float s = 0.0f;
  for (int b = 0; b < B_N; ++b) s += feats[b * NFEAT + j];
  const float mu = s * (1.0f / (float)B_N);
  float v = 0.0f;
  for (int b = 0; b < B_N; ++b) {
    const float d = feats[b * NFEAT + j] - mu;
    v += d * d;
  }
  v *= (1.0f / (float)B_N);
  stats[j] = mu;
  stats[NFEAT + j] = 1.0f / sqrtf(v + 1e-5f);
}

// ---------------- normalize + linear ----------------
__global__ __launch_bounds__(256) void out_kernel(
    const float* __restrict__ feats, const float* __restrict__ stats,
    const float* __restrict__ w, const float* __restrict__ lb,
    float* __restrict__ out) {
  const int b = blockIdx.x;
  const int tid = threadIdx.x;
  float acc0 = 0, acc1 = 0, acc2 = 0, acc3 = 0;
  for (int j = tid; j < NFEAT; j += 256) {
    const float v = (feats[b * NFEAT + j] - stats[j]) * stats[NFEAT + j];
    acc0 += v * w[0 * NFEAT + j];
    acc1 += v * w[1 * NFEAT + j];
    acc2 += v * w[2 * NFEAT + j];
    acc3 += v * w[3 * NFEAT + j];
  }
  __shared__ float red[4][256];
  red[0][tid] = acc0; red[1][tid] = acc1; red[2][tid] = acc2; red[3][tid] = acc3;
  __syncthreads();
  for (int s = 128; s > 0; s >>= 1) {
    if (tid < s) {
#pragma unroll
      for (int o = 0; o < 4; ++o) red[o][tid] += red[o][tid + s];
    }
    __syncthreads();
  }
  if (tid < 4) out[b * NOUT + tid] = red[tid][0] + lb[tid];
}

extern "C" void kernel_launch(void* const* d_in, const int* in_sizes, int n_in,
                              void* d_out, int out_size, void* d_ws, size_t ws_size,
                              hipStream_t stream) {
  const float* x  = (const float*)d_in[0];
  const float* fm = (const float*)d_in[1];
  const float* bw = (const float*)d_in[2];
  const float* sp = (const float*)d_in[3];
  const float* gd = (const float*)d_in[4];
  const float* lw = (const float*)d_in[5];
  const float* lb = (const float*)d_in[6];
  float* out = (float*)d_out;
  char* base = (char*)d_ws;

  // adaptive batch chunk: largest of {64,32,16} that fits ws
  const size_t fixed = OFF_U + (size_t)G_BYTES + (size_t)B_N * NFEAT * 4 + 2 * NFEAT * 4;
  int CB = 64;
  if (ws_size < fixed + (size_t)64 * 2097152) CB = 32;
  if (ws_size < fixed + (size_t)32 * 2097152) CB = 16;
  const int nchunk = B_N / CB;

  const size_t u_bytes = (size_t)CB * 1048576;  // per component array
  float*    filt  = (float*)base;
  _Float16* Urg   = (_Float16*)(base + OFF_U);
  _Float16* Uig   = (_Float16*)(base + OFF_U + u_bytes);
  float*    Gp    = (float*)(base + OFF_U + 2 * u_bytes);
  float*    feats = (float*)(base + OFF_U + 2 * u_bytes + G_BYTES);
  float*    stats = feats + (size_t)B_N * NFEAT;

  filter_kernel<<<1, 256, 0, stream>>>(fm, bw, sp, gd, filt);

  for (int chunk = 0; chunk < nchunk; ++chunk) {
    fftfilt_kernel<<<CB * C_N, 256, 0, stream>>>(x, filt, Urg, Uig, chunk * CB);
    gram_kernel<<<CB * 2 * TSG, 256, 0, stream>>>(Urg, Uig, Gp, chunk * CB * 2);
  }

  plv_kernel<<<(B_N * NFILT * NPAIRS + 255) / 256, 256, 0, stream>>>(Gp, feats);
  stats_kernel<<<(NFEAT + 255) / 256, 256, 0, stream>>>(feats, stats);
  out_kernel<<<B_N, 256, 0, stream>>>(feats, stats, lw, lb, out);
}

// Round 8
// 211.312 us; speedup vs baseline: 1.0623x; 1.0623x over previous
//
#include <hip/hip_runtime.h>
#include <math.h>

#define T_N     4096
#define B_N     64
#define C_N     64
#define NFILT   2
#define F_BINS  2049
#define NPAIRS  2016
#define NFEAT   4032
#define NOUT    4
#define TSG     4
#define NKS     32            // (4096/TSG)/32 K-steps per gram block

#define PI_F 3.14159265358979323846f

typedef _Float16 f16x8 __attribute__((ext_vector_type(8)));
typedef _Float16 f16x2 __attribute__((ext_vector_type(2)));
typedef float    f32x4 __attribute__((ext_vector_type(4)));

// ---------------------------------------------------------------------------
// Spectrum layout of the 3-phase register FFT (N = 16*16*16):
//   thread t = k1*16 + j1, register q = j2  holds bin k = q*256 + j1*16 + k1.
// Filter table stored at p(k) = (k & 0xF00) + ((k & 15) << 4) + ((k >> 4) & 15).
// Twiddles via v_sin/v_cos with EXACT revolution arguments (|r|<1, no range
// reduction): e^{i*2pi*r}. Same HW precision class as __sincosf (validated
// r7: absmax unchanged). X spectrum cached in f16x2 (16 VGPRs) to stay below
// the 128-VGPR occupancy cliff (r7 post-mortem: 132 VGPR halved occupancy).
// ---------------------------------------------------------------------------

// ---- ws layout (bytes) ----
#define OFF_U     65536
#define G_BYTES   (128 * TSG * 12288 * 4)

// ---------------- filter construction (1 block) ----------------
__global__ __launch_bounds__(256) void filter_kernel(
    const float* __restrict__ fm_, const float* __restrict__ bw_,
    const float* __restrict__ sp_, const float* __restrict__ gd_,
    float* __restrict__ filt) {
  __shared__ float smag[F_BINS];
  __shared__ float sred[256];
  const int tid = threadIdx.x;
  for (int f = 0; f < NFILT; ++f) {
    float* Fre = filt + f * 8192;
    float* Fim = Fre + 4096;
    for (int p = tid; p < 4096; p += 256) { Fre[p] = 0.0f; Fim[p] = 0.0f; }
    const float fm = fminf(fmaxf(fm_[f], 1.0f / 128.0f), 45.0f / 128.0f);
    const float bw = fminf(fmaxf(bw_[f], 1.0f / 128.0f), 1.0f);
    const float pp = fminf(fmaxf(sp_[f], 2.0f), 3.0f) * 8.0f - 14.0f;
    const float gd = gd_[f];
    const float scale = bw / (2.0f * powf(0.69314718055994531f, 1.0f / pp));
    float lmax = 0.0f;
    for (int i = tid; i < F_BINS; i += 256) {
      const float n = (float)i / 2048.0f;
      const float m = expf(-powf((fabsf(n - fm) + 1e-8f) / scale, pp));
      smag[i] = m;
      lmax = fmaxf(lmax, m);
    }
    sred[tid] = lmax;
    __syncthreads();
    for (int s = 128; s > 0; s >>= 1) {
      if (tid < s) sred[tid] = fmaxf(sred[tid], sred[tid + s]);
      __syncthreads();
    }
    const float inv = 1.0f / sred[0];
    __syncthreads();
    for (int k = tid; k < F_BINS; k += 256) {
      const float m = smag[k] * inv;
      const float pha = -gd * ((float)k * 0.125f) * PI_F;
      float sn, cs;
      sincosf(pha, &sn, &cs);
      const float dcs = (k == 0) ? 1.0f : 2.0f;
      const float sT = dcs * (1.0f / (float)T_N);
      const int p = (k & 0xF00) + ((k & 15) << 4) + ((k >> 4) & 15);
      Fre[p] = m * cs * sT;
      Fim[p] = m * sn * sT;
    }
    __syncthreads();
  }
}

// ---------------- complex helpers ----------------
__device__ __forceinline__ float2 cmul(float2 a, float c, float s) {
  return make_float2(a.x * c - a.y * s, a.x * s + a.y * c);
}
// e^{i*2pi*rev}, rev in revolutions, |rev| < 1
__device__ __forceinline__ float2 twid(float rev) {
  return make_float2(__builtin_amdgcn_cosf(rev), __builtin_amdgcn_sinf(rev));
}

// ---------------- 16-point DFT, natural order in/out, in registers ----------
template<int SGN>
__device__ __forceinline__ void dft16(float2* __restrict__ v) {
  const float sg = (float)SGN;
  const float C1 = 0.923879532511287f, S1 = 0.382683432365090f;
  const float Hh = 0.707106781186548f;
  float2 g[16];
#pragma unroll
  for (int n2 = 0; n2 < 4; ++n2) {
    const float2 a = v[n2], b = v[4 + n2], c = v[8 + n2], d = v[12 + n2];
    const float2 t0 = make_float2(a.x + c.x, a.y + c.y);
    const float2 t1 = make_float2(a.x - c.x, a.y - c.y);
    const float2 t2 = make_float2(b.x + d.x, b.y + d.y);
    const float2 t3 = make_float2(b.x - d.x, b.y - d.y);
    g[n2]      = make_float2(t0.x + t2.x, t0.y + t2.y);
    g[8 + n2]  = make_float2(t0.x - t2.x, t0.y - t2.y);
    g[4 + n2]  = make_float2(t1.x - sg * t3.y, t1.y + sg * t3.x);
    g[12 + n2] = make_float2(t1.x + sg * t3.y, t1.y - sg * t3.x);
  }
  g[5]  = cmul(g[5],  C1,  sg * S1);
  g[6]  = cmul(g[6],  Hh,  sg * Hh);
  g[7]  = cmul(g[7],  S1,  sg * C1);
  g[9]  = cmul(g[9],  Hh,  sg * Hh);
  g[10] = make_float2(-sg * g[10].y, sg * g[10].x);
  g[11] = cmul(g[11], -Hh, sg * Hh);
  g[13] = cmul(g[13], S1,  sg * C1);
  g[14] = cmul(g[14], -Hh, sg * Hh);
  g[15] = cmul(g[15], -C1, -sg * S1);
#pragma unroll
  for (int k1 = 0; k1 < 4; ++k1) {
    const float2 a = g[4 * k1], b = g[4 * k1 + 1];
    const float2 c = g[4 * k1 + 2], d = g[4 * k1 + 3];
    const float2 t0 = make_float2(a.x + c.x, a.y + c.y);
    const float2 t1 = make_float2(a.x - c.x, a.y - c.y);
    const float2 t2 = make_float2(b.x + d.x, b.y + d.y);
    const float2 t3 = make_float2(b.x - d.x, b.y - d.y);
    v[k1]      = make_float2(t0.x + t2.x, t0.y + t2.y);
    v[8 + k1]  = make_float2(t0.x - t2.x, t0.y - t2.y);
    v[4 + k1]  = make_float2(t1.x - sg * t3.y, t1.y + sg * t3.x);
    v[12 + k1] = make_float2(t1.x + sg * t3.y, t1.y - sg * t3.x);
  }
}

// transposes through padded float2 LDS (stride 264 -> ~2-way banks)
__device__ __forceinline__ void tr_cross_fwd(float2* __restrict__ v,
                                             float2* __restrict__ lds, int t) {
  __syncthreads();
#pragma unroll
  for (int k = 0; k < 16; ++k) lds[k * 264 + t] = v[k];
  __syncthreads();
  const int base = (t >> 4) * 264 + (t & 15);
#pragma unroll
  for (int m = 0; m < 16; ++m) v[m] = lds[base + m * 16];
}
__device__ __forceinline__ void tr_cross_inv(float2* __restrict__ v,
                                             float2* __restrict__ lds, int t) {
  __syncthreads();
  const int base = (t >> 4) * 264 + (t & 15);
#pragma unroll
  for (int m = 0; m < 16; ++m) lds[base + m * 16] = v[m];
  __syncthreads();
#pragma unroll
  for (int k = 0; k < 16; ++k) v[k] = lds[k * 264 + t];
}
__device__ __forceinline__ void tr_group(float2* __restrict__ v,
                                         float2* __restrict__ lds, int t) {
  __syncthreads();
  const int k1 = t >> 4, s = t & 15;
  const int rowb = k1 * 264;
#pragma unroll
  for (int r = 0; r < 16; ++r)
    lds[rowb + r * 16 + ((s + r) & 15)] = v[r];
  __syncthreads();
#pragma unroll
  for (int a = 0; a < 16; ++a)
    v[a] = lds[rowb + s * 16 + ((a + s) & 15)];
}

// ---------------- fwd FFT once + filter + 2x inverse FFT + normalize --------
__global__ __launch_bounds__(256) void fftfilt_kernel(
    const float* __restrict__ x, const float* __restrict__ filt,
    _Float16* __restrict__ Urg, _Float16* __restrict__ Uig, int chunkbase) {
  const int c  = blockIdx.x & 63;
  const int bb = blockIdx.x >> 6;
  const int b  = chunkbase + bb;
  const int t  = threadIdx.x;
  const int j1 = t & 15;
  __shared__ float2 lds[16 * 264];   // 33792 B

  float2 v[16];
  const float* xp = x + ((size_t)(b * C_N + c)) * T_N;
#pragma unroll
  for (int r = 0; r < 16; ++r) v[r] = make_float2(xp[r * 256 + t], 0.0f);

  // ---- forward ----
  dft16<-1>(v);
#pragma unroll
  for (int k = 1; k < 16; ++k) {               // chain A: e^{-2pi i t k/4096}
    const float2 w = twid((float)(t * k) * (-1.0f / 4096.0f));
    v[k] = cmul(v[k], w.x, w.y);
  }
  tr_cross_fwd(v, lds, t);
  dft16<-1>(v);
#pragma unroll
  for (int k = 1; k < 16; ++k) {               // chain B: e^{-2pi i j1 k/256}
    const float2 w = twid((float)(j1 * k) * (-1.0f / 256.0f));
    v[k] = cmul(v[k], w.x, w.y);
  }
  tr_group(v, lds, t);
  dft16<-1>(v);

  // cache spectrum packed f16x2 (16 VGPRs) — stay under the 128-VGPR cliff
  f16x2 X[16];
#pragma unroll
  for (int q = 0; q < 16; ++q)
    X[q] = f16x2{(_Float16)v[q].x, (_Float16)v[q].y};

#pragma unroll 1
  for (int f = 0; f < NFILT; ++f) {
    const float* Fre = filt + f * 8192;
    const float* Fim = Fre + 4096;
#pragma unroll
    for (int q = 0; q < 16; ++q) {             // component-wise filter
      v[q] = make_float2((float)X[q][0] * Fre[q * 256 + t],
                         (float)X[q][1] * Fim[q * 256 + t]);
    }
    // ---- inverse (mirror dataflow, conj twiddles, unscaled) ----
    dft16<1>(v);
#pragma unroll
    for (int k = 1; k < 16; ++k) {             // chain B': e^{+2pi i j1 k/256}
      const float2 w = twid((float)(j1 * k) * (1.0f / 256.0f));
      v[k] = cmul(v[k], w.x, w.y);
    }
    tr_group(v, lds, t);
    dft16<1>(v);
    {
      const int k1 = t >> 4, m2 = t & 15;
#pragma unroll
      for (int m1 = 0; m1 < 16; ++m1) {        // chain C: e^{+2pi i k1(m2+16m1)/4096}
        const float2 w = twid((float)(k1 * (m2 + 16 * m1)) * (1.0f / 4096.0f));
        v[m1] = cmul(v[m1], w.x, w.y);
      }
    }
    tr_cross_inv(v, lds, t);
    dft16<1>(v);

    const int sl = bb * 2 + f;
    _Float16* upr = Urg + ((size_t)sl * C_N + c) * T_N;
    _Float16* upi = Uig + ((size_t)sl * C_N + c) * T_N;
#pragma unroll
    for (int n1 = 0; n1 < 16; ++n1) {
      const float ir = rsqrtf(v[n1].x * v[n1].x + v[n1].y * v[n1].y + 1e-6f);
      upr[n1 * 256 + t] = (_Float16)(v[n1].x * ir);
      upi[n1 * 256 + t] = (_Float16)(v[n1].y * ir);
    }
  }
}

// ---------------- gram via f16 MFMA -> per-tsplit partial planes ------------
__global__ __launch_bounds__(256) void gram_kernel(
    const _Float16* __restrict__ Urg, const _Float16* __restrict__ Uig,
    float* __restrict__ Gp, int slicebase) {
  const int sl = blockIdx.x / TSG;
  const int ts = blockIdx.x % TSG;
  const int tid = threadIdx.x;
  const int w = tid >> 6;
  const int lane = tid & 63;
  __shared__ _Float16 sUr[2][64 * 40], sUi[2][64 * 40];

  const int row = tid >> 2, quarter = tid & 3;
  const size_t goff = (size_t)sl * C_N * T_N + (size_t)row * T_N
                      + ts * (T_N / TSG) + quarter * 8;
  const int loff = row * 40 + quarter * 8;
  const int frow = (lane & 15) * 40 + (lane >> 4) * 8;
  const int aoff = w * 640 + frow;

  f32x4 accRr[4] = {}, accIi[4] = {}, accRi[4] = {};

  f16x8 rr = *(const f16x8*)&Urg[goff];
  f16x8 ri = *(const f16x8*)&Uig[goff];
  int cur = 0;
  for (int ks = 0; ks < NKS; ++ks) {
    *(f16x8*)&sUr[cur][loff] = rr;
    *(f16x8*)&sUi[cur][loff] = ri;
    if (ks + 1 < NKS) {
      rr = *(const f16x8*)&Urg[goff + (ks + 1) * 32];
      ri = *(const f16x8*)&Uig[goff + (ks + 1) * 32];
    }
    __syncthreads();
    const f16x8 ar = *(const f16x8*)&sUr[cur][aoff];
    const f16x8 ai = *(const f16x8*)&sUi[cur][aoff];
#pragma unroll
    for (int n = 0; n < 4; ++n) {
      const f16x8 br = *(const f16x8*)&sUr[cur][n * 640 + frow];
      const f16x8 bi = *(const f16x8*)&sUi[cur][n * 640 + frow];
      accRr[n] = __builtin_amdgcn_mfma_f32_16x16x32_f16(ar, br, accRr[n], 0, 0, 0);
      accIi[n] = __builtin_amdgcn_mfma_f32_16x16x32_f16(ai, bi, accIi[n], 0, 0, 0);
      accRi[n] = __builtin_amdgcn_mfma_f32_16x16x32_f16(ar, bi, accRi[n], 0, 0, 0);
    }
    cur ^= 1;
  }

  // plain stores into this block's own partial plane (no atomics)
  float* Gs = Gp + (size_t)((slicebase + sl) * TSG + ts) * 12288;
  const int r0 = w * 16 + (lane >> 4) * 4;
  const int c0 = lane & 15;
#pragma unroll
  for (int n = 0; n < 4; ++n) {
    const bool upper = (n >= w);   // strictly-below-diagonal Rr/Ii never read
#pragma unroll
    for (int e = 0; e < 4; ++e) {
      const int idx = (r0 + e) * 64 + n * 16 + c0;
      if (upper) {
        Gs[idx] = accRr[n][e];
        Gs[4096 + idx] = accIi[n][e];
      }
      Gs[8192 + idx] = accRi[n][e];
    }
  }
}

// ---------------- PLV (sums TSG partials) + scatter to feature layout -------
__global__ __launch_bounds__(256) void plv_kernel(
    const float* __restrict__ Gp, float* __restrict__ feats) {
  const int idx = blockIdx.x * 256 + threadIdx.x;
  if (idx >= B_N * NFILT * NPAIRS) return;
  const int slice = idx / NPAIRS;
  const int p = idx - slice * NPAIRS;
  const int b = slice >> 1, f = slice & 1;
  int c = 0, rem = p;
  while (rem >= 63 - c) { rem -= 63 - c; ++c; }
  const int d = c + 1 + rem;
  const float* Gs = Gp + (size_t)slice * TSG * 12288;
  float rr = 0, ii = 0, ri = 0, ir = 0;
#pragma unroll
  for (int ts = 0; ts < TSG; ++ts) {
    const float* P = Gs + ts * 12288;
    rr += P[c * 64 + d];
    ii += P[4096 + c * 64 + d];
    ri += P[8192 + c * 64 + d];
    ir += P[8192 + d * 64 + c];
  }
  const float cre = rr + ii;
  const float cim = ri - ir;
  const float plv = sqrtf(cre * cre + cim * cim + 1e-6f) * (1.0f / (float)T_N);
  feats[b * NFEAT + p * NFILT + f] = plv;
}

// ---------------- batch stats (training-mode BN, biased var) ----------------
__global__ __launch_bounds__(256) void stats_kernel(
    const float* __restrict__ feats, float* __restrict__ stats) {
  const int j = blockIdx.x * 256 + threadIdx.x;
  if (j >= NFEAT) return;
  float s = 0.0f;
  for (int b = 0; b < B_N; ++b) s += feats[b * NFEAT + j];
  const float mu = s * (1.0f / (float)B_N);
  float v = 0.0f;
  for (int b = 0; b < B_N; ++b) {
    const float d = feats[b * NFEAT + j] - mu;
    v += d * d;
  }
  v *= (1.0f / (float)B_N);
  stats[j] = mu;
  stats[NFEAT + j] = 1.0f / sqrtf(v + 1e-5f);
}

// ---------------- normalize + linear ----------------
__global__ __launch_bounds__(256) void out_kernel(
    const float* __restrict__ feats, const float* __restrict__ stats,
    const float* __restrict__ w, const float* __restrict__ lb,
    float* __restrict__ out) {
  const int b = blockIdx.x;
  const int tid = threadIdx.x;
  float acc0 = 0, acc1 = 0, acc2 = 0, acc3 = 0;
  for (int j = tid; j < NFEAT; j += 256) {
    const float v = (feats[b * NFEAT + j] - stats[j]) * stats[NFEAT + j];
    acc0 += v * w[0 * NFEAT + j];
    acc1 += v * w[1 * NFEAT + j];
    acc2 += v * w[2 * NFEAT + j];
    acc3 += v * w[3 * NFEAT + j];
  }
  __shared__ float red[4][256];
  red[0][tid] = acc0; red[1][tid] = acc1; red[2][tid] = acc2; red[3][tid] = acc3;
  __syncthreads();
  for (int s = 128; s > 0; s >>= 1) {
    if (tid < s) {
#pragma unroll
      for (int o = 0; o < 4; ++o) red[o][tid] += red[o][tid + s];
    }
    __syncthreads();
  }
  if (tid < 4) out[b * NOUT + tid] = red[tid][0] + lb[tid];
}

extern "C" void kernel_launch(void* const* d_in, const int* in_sizes, int n_in,
                              void* d_out, int out_size, void* d_ws, size_t ws_size,
                              hipStream_t stream) {
  const float* x  = (const float*)d_in[0];
  const float* fm = (const float*)d_in[1];
  const float* bw = (const float*)d_in[2];
  const float* sp = (const float*)d_in[3];
  const float* gd = (const float*)d_in[4];
  const float* lw = (const float*)d_in[5];
  const float* lb = (const float*)d_in[6];
  float* out = (float*)d_out;
  char* base = (char*)d_ws;

  // adaptive batch chunk: largest of {64,32,16} that fits ws
  const size_t fixed = OFF_U + (size_t)G_BYTES + (size_t)B_N * NFEAT * 4 + 2 * NFEAT * 4;
  int CB = 64;
  if (ws_size < fixed + (size_t)64 * 2097152) CB = 32;
  if (ws_size < fixed + (size_t)32 * 2097152) CB = 16;
  const int nchunk = B_N / CB;

  const size_t u_bytes = (size_t)CB * 1048576;  // per component array
  float*    filt  = (float*)base;
  _Float16* Urg   = (_Float16*)(base + OFF_U);
  _Float16* Uig   = (_Float16*)(base + OFF_U + u_bytes);
  float*    Gp    = (float*)(base + OFF_U + 2 * u_bytes);
  float*    feats = (float*)(base + OFF_U + 2 * u_bytes + G_BYTES);
  float*    stats = feats + (size_t)B_N * NFEAT;

  filter_kernel<<<1, 256, 0, stream>>>(fm, bw, sp, gd, filt);

  for (int chunk = 0; chunk < nchunk; ++chunk) {
    fftfilt_kernel<<<CB * C_N, 256, 0, stream>>>(x, filt, Urg, Uig, chunk * CB);
    gram_kernel<<<CB * 2 * TSG, 256, 0, stream>>>(Urg, Uig, Gp, chunk * CB * 2);
  }

  plv_kernel<<<(B_N * NFILT * NPAIRS + 255) / 256, 256, 0, stream>>>(Gp, feats);
  stats_kernel<<<(NFEAT + 255) / 256, 256, 0, stream>>>(feats, stats);
  out_kernel<<<B_N, 256, 0, stream>>>(feats, stats, lw, lb, out);
}